// Round 8
// baseline (201.270 us; speedup 1.0000x reference)
//
#include <hip/hip_runtime.h>
#include <hip/hip_bf16.h>
#include <stdint.h>

#define K_DIM 20000
#define N_DIM 512
#define M_DIM 2048

#define BM 128
#define BN 128
#define BK 32              // 32 bf16 = 64 B per LDS row = 4 x 16B chunks
#define NSTEPS 625         // K_DIM / BK (exact)
#define SPLITS 8           // 64 tiles * 8 = 512 blocks = 2 blocks/CU exact
#define GRID (64 * SPLITS)
#define GEMM_THREADS 256

typedef __bf16 bf16_t;
typedef bf16_t  bf16x8 __attribute__((ext_vector_type(8)));
typedef float   f32x4  __attribute__((ext_vector_type(4)));
typedef uint32_t u32x4 __attribute__((ext_vector_type(4)));

__device__ __forceinline__ uint32_t pack_bf16x2(float a, float b) {
  uint32_t ua = (uint32_t)__builtin_bit_cast(uint16_t, (bf16_t)a);
  uint32_t ub = (uint32_t)__builtin_bit_cast(uint16_t, (bf16_t)b);
  return ua | (ub << 16);
}

// async global->LDS, 16B per lane. LDS dest is wave-uniform base + lane*16
// (linear); global src is per-lane (pre-swizzled to match swizzled reads).
__device__ __forceinline__ void gload16(const uint16_t* g, uint16_t* l) {
  __builtin_amdgcn_global_load_lds(
      (const __attribute__((address_space(1))) void*)g,
      (__attribute__((address_space(3))) void*)l, 16, 0, 0);
}

// ---------------------------------------------------------------------------
// Kernel 0: E (K x N fp32, row-major) -> Bt (N x K bf16, row-major)
// ---------------------------------------------------------------------------
__global__ __launch_bounds__(256)
void bt_transpose_kernel(const float* __restrict__ B, uint16_t* __restrict__ Bt) {
  const int kb = blockIdx.x;      // 0..624
  const int nb = blockIdx.y;      // 0..7
  const int t  = threadIdx.x;
  const int rn = t >> 2;          // 0..63 local n
  const int kc = t & 3;           // 0..3  (8 k each)
  const int n  = nb * 64 + rn;
  const int kk = kb * 32 + kc * 8;

  float v[8];
#pragma unroll
  for (int j = 0; j < 8; ++j)
    v[j] = B[(size_t)(kk + j) * N_DIM + n];

  u32x4 q;
#pragma unroll
  for (int j = 0; j < 4; ++j)
    q[j] = pack_bf16x2(v[2 * j], v[2 * j + 1]);

  *reinterpret_cast<u32x4*>(&Bt[(size_t)n * K_DIM + kk]) = q;
}

// ---------------------------------------------------------------------------
// Kernel 1: out[m][n] = bias[n]   (accumulation target for split-K atomics)
// ---------------------------------------------------------------------------
__global__ __launch_bounds__(256)
void init_out_kernel(const float* __restrict__ bias, float* __restrict__ out) {
  const int i = blockIdx.x * 256 + threadIdx.x;
  out[i] = bias[i & (N_DIM - 1)];
}

// ---------------------------------------------------------------------------
// Kernel 2: split-K bf16 MFMA GEMM, 128x128 tile, 4 waves (2x2), BK=32.
//   A (x fp32): DIRECT global -> registers -> cvt_pk -> MFMA A-fragment.
//       No A LDS, no pack/ds_write, no A barrier coupling. 2-deep prefetch,
//       parity-unrolled: step i consumes set[i&1] then overwrites it with
//       A(i+2) (consume-before-load, no register copies).
//   B (Bt bf16): gload_lds into ring of 4 LDS buffers (2-deep prefetch),
//       pre-swizzled per-lane source, swizzled frag reads (R3: BC=0).
//   Per-wave vmcnt FIFO at end of step i (issue order B(i+2)x2 ... A(i+2)x8):
//       outstanding = B(i+1)2 A(i+1)8 B(i+2)2 A(i+2)8 = 20; vmcnt(18)
//       drains exactly B(i+1). Tail: vmcnt(8) at nsteps-2, none at last.
//   Barrier protects only the B ring (raw s_barrier, no compiler drain).
// LDS = 4 x 8 KB = 32 KB. grid 512 = 2 blocks/CU exact; XCD x <- split s=x
// so each XCD's Bt k-slice (2.56 MB) is L2-resident.
// ---------------------------------------------------------------------------
__global__ __launch_bounds__(GEMM_THREADS)
void gemm_split_kernel(const float* __restrict__ X,
                       const uint16_t* __restrict__ Bt,
                       float* __restrict__ out) {
  __shared__ __align__(16) uint16_t Bl[4][BN * 32];   // 8 KB each (ring of 4)

  // XCD-chunk swizzle: phys&7 = XCD gets contiguous logical range of 64 bids
  // = {all 16 mt x 4 nt} of split s = XCD.
  const int phys = blockIdx.x;
  const int bid  = (phys & 7) * (GRID / 8) + (phys >> 3);
  const int mt    = bid & 15;         // m-tile 0..15
  const int chunk = bid >> 4;         // 0..31
  const int nt    = chunk & 3;        // n-tile 0..3
  const int s     = chunk >> 2;       // K-split 0..7
  const int m0 = mt * BM;
  const int n0 = nt * BN;
  const int step0 = (s * NSTEPS) / SPLITS;
  const int step1 = ((s + 1) * NSTEPS) / SPLITS;
  const int nsteps = step1 - step0;   // 78 or 79

  const int t    = threadIdx.x;
  const int wid  = t >> 6;
  const int lane = t & 63;
  const int wr  = (wid >> 1) * 64;  // wave row offset in tile
  const int wc  = (wid & 1) * 64;   // wave col offset in tile
  const int l15 = lane & 15;
  const int l16 = lane >> 4;        // 0..3

  // --- A direct-load base: lane covers A[m0+wr+mf*16+l15][k0 + l16*8 .. +8]
  const float* __restrict__ abase =
      X + (size_t)(m0 + wr + l15) * K_DIM + step0 * BK + l16 * 8;

  // --- B gload_lds decomposition: wave w, call q covers rows w*32+q*16..+16
  const int brow0 = wid * 32 + (lane >> 2);          // rows for q=0 (q=1: +16)
  const int bch   = (lane & 3) ^ ((brow0 >> 1) & 3); // src chunk (swizzle inv.)
  const uint16_t* __restrict__ bsrc0 =
      Bt + (size_t)(n0 + brow0) * K_DIM + step0 * BK + bch * 8;
  const uint16_t* __restrict__ bsrc1 = bsrc0 + (size_t)16 * K_DIM;
  const int bdst0 = wid * 1024;     // ushort offset of wave's q=0 chunk
  const int bdst1 = bdst0 + 512;

  // --- B frag read offset (chunk swizzle is nf-invariant)
  const int fchunk = ((l16 ^ ((l15 >> 1) & 3)) << 3);

  f32x4 acc[4][4] = {};
  // A prefetch sets: parity 0 / parity 1, each 4 mf x (lo,hi) f32x4
  f32x4 aL0[4], aH0[4], aL1[4], aH1[4];

  // ---- prologue: B(0)->ring0, B(1)->ring1; A(0)->set0, A(1)->set1 ----
  gload16(bsrc0, &Bl[0][bdst0]);
  gload16(bsrc1, &Bl[0][bdst1]);
  gload16(bsrc0 + BK, &Bl[1][bdst0]);
  gload16(bsrc1 + BK, &Bl[1][bdst1]);
  __builtin_amdgcn_sched_barrier(0);
#pragma unroll
  for (int mf = 0; mf < 4; ++mf) {
    aL0[mf] = *reinterpret_cast<const f32x4*>(abase + (size_t)mf * 16 * K_DIM);
    aH0[mf] = *reinterpret_cast<const f32x4*>(abase + (size_t)mf * 16 * K_DIM + 4);
  }
#pragma unroll
  for (int mf = 0; mf < 4; ++mf) {
    aL1[mf] = *reinterpret_cast<const f32x4*>(abase + (size_t)mf * 16 * K_DIM + BK);
    aH1[mf] = *reinterpret_cast<const f32x4*>(abase + (size_t)mf * 16 * K_DIM + BK + 4);
  }
  // outstanding: B0(2) B1(2) A0(8) A1(8) = 20; drain B(0) only.
  asm volatile("s_waitcnt vmcnt(18)" ::: "memory");
  __builtin_amdgcn_s_barrier();
  __builtin_amdgcn_sched_barrier(0);

  // ---- main loop, unrolled by 2 (static A register sets) ----
#define GEMM_STEP(I, AL, AH)                                                   \
  {                                                                            \
    const bool have1 = ((I) + 1 < nsteps);                                     \
    const bool have2 = ((I) + 2 < nsteps);                                     \
    const int koff2 = ((I) + 2) * BK;                                          \
    if (have2) {                                                               \
      uint16_t* bb = &Bl[((I) + 2) & 3][0];                                    \
      gload16(bsrc0 + koff2, bb + bdst0);                                      \
      gload16(bsrc1 + koff2, bb + bdst1);                                      \
    }                                                                          \
    __builtin_amdgcn_sched_barrier(0);                                         \
    /* cvt A(I) from the parity set (compiler waits only on these 8 loads) */  \
    bf16x8 afr[4];                                                             \
    _Pragma("unroll")                                                          \
    for (int mf = 0; mf < 4; ++mf) {                                           \
      u32x4 w;                                                                 \
      w[0] = pack_bf16x2(AL[mf][0], AL[mf][1]);                                \
      w[1] = pack_bf16x2(AL[mf][2], AL[mf][3]);                                \
      w[2] = pack_bf16x2(AH[mf][0], AH[mf][1]);                                \
      w[3] = pack_bf16x2(AH[mf][2], AH[mf][3]);                                \
      afr[mf] = __builtin_bit_cast(bf16x8, w);                                 \
    }                                                                          \
    const uint16_t* __restrict__ Br = &Bl[(I) & 3][0];                         \
    bf16x8 bfr[4];                                                             \
    _Pragma("unroll")                                                          \
    for (int nf = 0; nf < 4; ++nf)                                             \
      bfr[nf] = *reinterpret_cast<const bf16x8*>(                              \
          &Br[(wc + nf * 16 + l15) * 32 + fchunk]);                            \
    _Pragma("unroll")                                                          \
    for (int mf = 0; mf < 4; ++mf)                                             \
      _Pragma("unroll")                                                        \
      for (int nf = 0; nf < 4; ++nf)                                           \
        acc[mf][nf] = __builtin_amdgcn_mfma_f32_16x16x32_bf16(                 \
            afr[mf], bfr[nf], acc[mf][nf], 0, 0, 0);                           \
    /* overwrite the just-consumed set with A(I+2) */                          \
    if (have2) {                                                               \
      _Pragma("unroll")                                                        \
      for (int mf = 0; mf < 4; ++mf) {                                         \
        AL[mf] = *reinterpret_cast<const f32x4*>(                              \
            abase + (size_t)mf * 16 * K_DIM + koff2);                          \
        AH[mf] = *reinterpret_cast<const f32x4*>(                              \
            abase + (size_t)mf * 16 * K_DIM + koff2 + 4);                      \
      }                                                                        \
    }                                                                          \
    if (have2) {                                                               \
      /* drain B(I+1); keep A(I+1)8 + B(I+2)2 + A(I+2)8 in flight */           \
      asm volatile("s_waitcnt vmcnt(18)" ::: "memory");                        \
      __builtin_amdgcn_s_barrier();                                            \
      __builtin_amdgcn_sched_barrier(0);                                       \
    } else if (have1) {                                                        \
      /* outstanding: B(last)2 + A(last)8 = 10; drain B(last) */               \
      asm volatile("s_waitcnt vmcnt(8)" ::: "memory");                         \
      __builtin_amdgcn_s_barrier();                                            \
      __builtin_amdgcn_sched_barrier(0);                                       \
    }                                                                          \
  }

  for (int i = 0; i < nsteps; i += 2) {
    GEMM_STEP(i, aL0, aH0);
    if (i + 1 < nsteps) GEMM_STEP(i + 1, aL1, aH1);
  }
#undef GEMM_STEP

  // epilogue: scaled atomic accumulation (C/D: col = lane&15, row = (lane>>4)*4 + j)
  const float scale = 1.0f / (float)K_DIM;
#pragma unroll
  for (int mf = 0; mf < 4; ++mf) {
#pragma unroll
    for (int nf = 0; nf < 4; ++nf) {
      const int row = m0 + wr + mf * 16 + l16 * 4;
      const int col = n0 + wc + nf * 16 + l15;
#pragma unroll
      for (int j = 0; j < 4; ++j)
        atomicAdd(&out[(size_t)(row + j) * N_DIM + col], acc[mf][nf][j] * scale);
    }
  }
}

// ---------------------------------------------------------------------------
extern "C" void kernel_launch(void* const* d_in, const int* in_sizes, int n_in,
                              void* d_out, int out_size, void* d_ws, size_t ws_size,
                              hipStream_t stream) {
  (void)in_sizes; (void)n_in; (void)out_size; (void)ws_size;
  const float* x    = (const float*)d_in[0];
  const float* emb  = (const float*)d_in[1];
  const float* bias = (const float*)d_in[2];
  float*    out = (float*)d_out;
  uint16_t* bt  = (uint16_t*)d_ws;   // 512*20000*2 = 20.48 MB

  bt_transpose_kernel<<<dim3(K_DIM / 32, N_DIM / 64), 256, 0, stream>>>(emb, bt);
  init_out_kernel<<<(M_DIM * N_DIM) / 256, 256, 0, stream>>>(bias, out);
  gemm_split_kernel<<<GRID, GEMM_THREADS, 0, stream>>>(x, bt, out);
}

// Round 9
// 101.673 us; speedup vs baseline: 1.9796x; 1.9796x over previous
//
#include <hip/hip_runtime.h>
#include <hip/hip_bf16.h>
#include <stdint.h>

#define K_DIM 20000
#define N_DIM 512
#define M_DIM 2048

#define BM 128
#define BN 128
#define BK 32              // 32 bf16 = 64 B per LDS row = 4 x 16B chunks
#define NSTEPS 625         // K_DIM / BK (exact)
#define SPLITS 8           // 64 tiles * 8 = 512 blocks = 2 blocks/CU exact
#define GRID (64 * SPLITS)
#define GEMM_THREADS 256

typedef __bf16 bf16_t;
typedef bf16_t  bf16x8 __attribute__((ext_vector_type(8)));
typedef float   f32x4  __attribute__((ext_vector_type(4)));
typedef uint32_t u32x2 __attribute__((ext_vector_type(2)));
typedef uint32_t u32x4 __attribute__((ext_vector_type(4)));

__device__ __forceinline__ uint32_t pack_bf16x2(float a, float b) {
  uint32_t ua = (uint32_t)__builtin_bit_cast(uint16_t, (bf16_t)a);
  uint32_t ub = (uint32_t)__builtin_bit_cast(uint16_t, (bf16_t)b);
  return ua | (ub << 16);
}

// ---------------------------------------------------------------------------
// Kernel 0: E (K x N fp32, row-major) -> Bt (N x K bf16, row-major)
// ---------------------------------------------------------------------------
__global__ __launch_bounds__(256)
void bt_transpose_kernel(const float* __restrict__ B, uint16_t* __restrict__ Bt) {
  const int kb = blockIdx.x;      // 0..624
  const int nb = blockIdx.y;      // 0..7
  const int t  = threadIdx.x;
  const int rn = t >> 2;          // 0..63 local n
  const int kc = t & 3;           // 0..3  (8 k each)
  const int n  = nb * 64 + rn;
  const int kk = kb * 32 + kc * 8;

  float v[8];
#pragma unroll
  for (int j = 0; j < 8; ++j)
    v[j] = B[(size_t)(kk + j) * N_DIM + n];

  u32x4 q;
#pragma unroll
  for (int j = 0; j < 4; ++j)
    q[j] = pack_bf16x2(v[2 * j], v[2 * j + 1]);

  *reinterpret_cast<u32x4*>(&Bt[(size_t)n * K_DIM + kk]) = q;
}

// ---------------------------------------------------------------------------
// Kernel 1: out[m][n] = bias[n]   (accumulation target for split-K atomics)
// ---------------------------------------------------------------------------
__global__ __launch_bounds__(256)
void init_out_kernel(const float* __restrict__ bias, float* __restrict__ out) {
  const int i = blockIdx.x * 256 + threadIdx.x;
  out[i] = bias[i & (N_DIM - 1)];
}

// ---------------------------------------------------------------------------
// Kernel 2: split-K bf16 MFMA GEMM, 128x128 tile, 4 waves (2x2), BK=32.
// R1's proven reg-staged structure + three fixes:
//   (1) XOR-swizzled LDS (R2/R3: bank conflicts 1e7 -> 0), 2x16 KB dbuf.
//   (2) parity-unrolled 2 static register sets (no copies): step i loads
//       data(i+2) into set[i&1], packs data(i+1) from set[(i+1)&1] ->
//       compiler's vmcnt wait before pack retires loads a full step old.
//   (3) raw s_barrier + lgkmcnt(0) only -- reg-destined loads stay in
//       flight across the barrier (no vmcnt(0) drain of prefetch).
//   (4) XCD-chunked bid swizzle (R6: FETCH 165->122 MB); XCD x = split s.
// ---------------------------------------------------------------------------
__global__ __launch_bounds__(GEMM_THREADS)
void gemm_split_kernel(const float* __restrict__ X,
                       const uint16_t* __restrict__ Bt,
                       float* __restrict__ out) {
  __shared__ __align__(16) uint16_t Al[2][BM * 32];   // 8 KB each
  __shared__ __align__(16) uint16_t Bl[2][BN * 32];   // 8 KB each

  // XCD-chunk swizzle: XCD = phys&7 gets 64 consecutive logical bids
  // = all 16 mt x 4 nt of split s = XCD. Bt k-slice (2.5 MB) L2-resident.
  const int phys = blockIdx.x;
  const int bid  = (phys & 7) * (GRID / 8) + (phys >> 3);
  const int mt    = bid & 15;         // m-tile 0..15
  const int chunk = bid >> 4;         // 0..31
  const int nt    = chunk & 3;        // n-tile 0..3
  const int s     = chunk >> 2;       // K-split 0..7
  const int m0 = mt * BM;
  const int n0 = nt * BN;
  const int step0 = (s * NSTEPS) / SPLITS;
  const int step1 = ((s + 1) * NSTEPS) / SPLITS;
  const int nsteps = step1 - step0;   // 78 or 79

  const int t    = threadIdx.x;
  const int wid  = t >> 6;
  const int lane = t & 63;
  const int wr  = (wid >> 1) * 64;  // wave row offset in tile
  const int wc  = (wid & 1) * 64;   // wave col offset in tile
  const int l15 = lane & 15;
  const int l16 = lane >> 4;        // 0..3

  // --- A staging: 4 passes of 32 rows; thread owns one f32x4 (16B) per pass
  const int arow = t >> 3;          // 0..31
  const int af4  = t & 7;           // f32x4 chunk in row
  const int aswz = (arow >> 1) & 3; // row bits[2:1], invariant under +32p
  const int aoff = ((af4 >> 1) ^ aswz) * 8 + (af4 & 1) * 4;  // ushort offset
  const float* __restrict__ xptr =
      X + (size_t)(m0 + arow) * K_DIM + step0 * BK + af4 * 4;

  // --- B staging: 2 passes of 64 rows; thread owns one u32x4 (16B) per pass
  const int brow = t >> 2;          // 0..63
  const int bch  = t & 3;           // 16B chunk
  const int bswz = (brow >> 1) & 3; // invariant under +64p
  const int boff = ((bch ^ bswz) << 3);
  const uint16_t* __restrict__ btptr =
      Bt + (size_t)(n0 + brow) * K_DIM + step0 * BK + bch * 8;

  // --- frag read chunk (swizzle is mf/nf-invariant: row bits[2:1] = l15 bits)
  const int fchunk = ((l16 ^ ((l15 >> 1) & 3)) << 3);

  f32x4 acc[4][4] = {};
  // two static register sets (parity): data d lives in set[d&1]
  f32x4 aS0[4], aS1[4];
  u32x4 bS0[2], bS1[2];

  // ---- prologue: load data0 -> set0, data1 -> set1; pack data0 -> buf0 ----
#pragma unroll
  for (int p = 0; p < 4; ++p)
    aS0[p] = *reinterpret_cast<const f32x4*>(xptr + (size_t)p * 32 * K_DIM);
#pragma unroll
  for (int p = 0; p < 2; ++p)
    bS0[p] = *reinterpret_cast<const u32x4*>(btptr + (size_t)p * 64 * K_DIM);
  if (1 < nsteps) {
#pragma unroll
    for (int p = 0; p < 4; ++p)
      aS1[p] = *reinterpret_cast<const f32x4*>(xptr + (size_t)p * 32 * K_DIM + BK);
#pragma unroll
    for (int p = 0; p < 2; ++p)
      bS1[p] = *reinterpret_cast<const u32x4*>(btptr + (size_t)p * 64 * K_DIM + BK);
  }
#pragma unroll
  for (int p = 0; p < 4; ++p) {
    u32x2 w;
    w[0] = pack_bf16x2(aS0[p][0], aS0[p][1]);
    w[1] = pack_bf16x2(aS0[p][2], aS0[p][3]);
    *reinterpret_cast<u32x2*>(&Al[0][(arow + p * 32) * 32 + aoff]) = w;
  }
#pragma unroll
  for (int p = 0; p < 2; ++p)
    *reinterpret_cast<u32x4*>(&Bl[0][(brow + p * 64) * 32 + boff]) = bS0[p];
  asm volatile("s_waitcnt lgkmcnt(0)" ::: "memory");
  __builtin_amdgcn_s_barrier();
  __builtin_amdgcn_sched_barrier(0);

  // ---- main loop, unrolled by 2 (static register sets, rule #20) ----
#define GEMM_STEP(I, SLA, SLB, SPA, SPB)                                       \
  {                                                                            \
    const bool have1 = ((I) + 1 < nsteps);                                     \
    const bool have2 = ((I) + 2 < nsteps);                                     \
    if (have2) {                                                               \
      const int koff = ((I) + 2) * BK;                                         \
      _Pragma("unroll")                                                        \
      for (int p = 0; p < 4; ++p)                                              \
        SLA[p] = *reinterpret_cast<const f32x4*>(                              \
            xptr + (size_t)p * 32 * K_DIM + koff);                             \
      _Pragma("unroll")                                                        \
      for (int p = 0; p < 2; ++p)                                              \
        SLB[p] = *reinterpret_cast<const u32x4*>(                              \
            btptr + (size_t)p * 64 * K_DIM + koff);                            \
    }                                                                          \
    __builtin_amdgcn_sched_barrier(0); /* pin prefetch issue before compute */ \
    const uint16_t* __restrict__ Ar = &Al[(I) & 1][0];                         \
    const uint16_t* __restrict__ Br = &Bl[(I) & 1][0];                         \
    bf16x8 afr[4], bfr[4];                                                     \
    _Pragma("unroll")                                                          \
    for (int mf = 0; mf < 4; ++mf)                                             \
      afr[mf] = *reinterpret_cast<const bf16x8*>(                              \
          &Ar[(wr + mf * 16 + l15) * 32 + fchunk]);                            \
    _Pragma("unroll")                                                          \
    for (int nf = 0; nf < 4; ++nf)                                             \
      bfr[nf] = *reinterpret_cast<const bf16x8*>(                              \
          &Br[(wc + nf * 16 + l15) * 32 + fchunk]);                            \
    _Pragma("unroll")                                                          \
    for (int mf = 0; mf < 4; ++mf)                                             \
      _Pragma("unroll")                                                        \
      for (int nf = 0; nf < 4; ++nf)                                           \
        acc[mf][nf] = __builtin_amdgcn_mfma_f32_16x16x32_bf16(                 \
            afr[mf], bfr[nf], acc[mf][nf], 0, 0, 0);                           \
    if (have1) { /* pack data(I+1), loaded a full step ago (landed) */         \
      uint16_t* Aw = &Al[((I) + 1) & 1][0];                                    \
      uint16_t* Bw = &Bl[((I) + 1) & 1][0];                                    \
      _Pragma("unroll")                                                        \
      for (int p = 0; p < 4; ++p) {                                            \
        u32x2 w;                                                               \
        w[0] = pack_bf16x2(SPA[p][0], SPA[p][1]);                              \
        w[1] = pack_bf16x2(SPA[p][2], SPA[p][3]);                              \
        *reinterpret_cast<u32x2*>(&Aw[(arow + p * 32) * 32 + aoff]) = w;       \
      }                                                                        \
      _Pragma("unroll")                                                        \
      for (int p = 0; p < 2; ++p)                                              \
        *reinterpret_cast<u32x4*>(&Bw[(brow + p * 64) * 32 + boff]) = SPB[p];  \
    }                                                                          \
    /* raw barrier: drain LDS ops only; reg loads stay in flight */            \
    asm volatile("s_waitcnt lgkmcnt(0)" ::: "memory");                         \
    __builtin_amdgcn_s_barrier();                                              \
    __builtin_amdgcn_sched_barrier(0);                                         \
  }

  for (int i = 0; i < nsteps; i += 2) {
    GEMM_STEP(i, aS0, bS0, aS1, bS1);
    if (i + 1 < nsteps) GEMM_STEP(i + 1, aS1, bS1, aS0, bS0);
  }
#undef GEMM_STEP

  // epilogue: scaled atomic accumulation (C/D: col = lane&15, row = (lane>>4)*4 + j)
  const float scale = 1.0f / (float)K_DIM;
#pragma unroll
  for (int mf = 0; mf < 4; ++mf) {
#pragma unroll
    for (int nf = 0; nf < 4; ++nf) {
      const int row = m0 + wr + mf * 16 + l16 * 4;
      const int col = n0 + wc + nf * 16 + l15;
#pragma unroll
      for (int j = 0; j < 4; ++j)
        atomicAdd(&out[(size_t)(row + j) * N_DIM + col], acc[mf][nf][j] * scale);
    }
  }
}

// ---------------------------------------------------------------------------
extern "C" void kernel_launch(void* const* d_in, const int* in_sizes, int n_in,
                              void* d_out, int out_size, void* d_ws, size_t ws_size,
                              hipStream_t stream) {
  (void)in_sizes; (void)n_in; (void)out_size; (void)ws_size;
  const float* x    = (const float*)d_in[0];
  const float* emb  = (const float*)d_in[1];
  const float* bias = (const float*)d_in[2];
  float*    out = (float*)d_out;
  uint16_t* bt  = (uint16_t*)d_ws;   // 512*20000*2 = 20.48 MB

  bt_transpose_kernel<<<dim3(K_DIM / 32, N_DIM / 64), 256, 0, stream>>>(emb, bt);
  init_out_kernel<<<(M_DIM * N_DIM) / 256, 256, 0, stream>>>(bias, out);
  gemm_split_kernel<<<GRID, GEMM_THREADS, 0, stream>>>(x, bt, out);
}